// Round 7
// baseline (221.356 us; speedup 1.0000x reference)
//
#include <hip/hip_runtime.h>
#include <hip/hip_bf16.h>
#include <cstdint>
#include <cstddef>

// Problem constants
#define B_N 8192
#define D_K 1024
#define H_N 400
#define HP  416          // H padded to multiple of 32
#define HPAD 424         // h1 LDS row stride in shorts (bank-skew)
#define K2_N 512
#define E_N 16
#define L_N 256
#define TMR 16                        // rows per block (row-strip)
#define PAD_ROWS (B_N + E_N * TMR)    // 8448
#define NT2 (PAD_ROWS / TMR)          // 528 = 8 XCDs * 66

typedef short bf16x8 __attribute__((ext_vector_type(8)));
typedef float f32x4 __attribute__((ext_vector_type(4)));

// async global->LDS, 16B per lane; LDS dest = wave-uniform base + lane*16.
// Global address may be fully per-lane (gather OK).
#define GLDS(gp, lp) __builtin_amdgcn_global_load_lds( \
    (const __attribute__((address_space(1))) unsigned int*)(gp), \
    (__attribute__((address_space(3))) unsigned int*)(lp), 16, 0, 0)

static __device__ __forceinline__ unsigned short f2bf(float f) {
  union { float f; unsigned int u; } c; c.f = f;
  unsigned int u = c.u + 0x7fffu + ((c.u >> 16) & 1u);  // RNE
  return (unsigned short)(u >> 16);
}
static __device__ __forceinline__ unsigned int pkbf(float a, float b) {
  union { __hip_bfloat162 v; unsigned int u; } c;
  c.v = __float22bfloat162_rn(make_float2(a, b));
  return c.u;
}

// ---------------- prep (one launch, fully parallel blocks): ----------------
// [0,1792):    W1 transpose [1024][400] f32 -> [416][1024] bf16 (zero-pad)
// [1792,2688): W2 transpose [400][512] f32 -> [512][416] bf16 (zero-pad)
// [2688,3200): x convert f32 -> bf16 (16 rows/block)
// [3200,3232): scatter (hist self-computed per block from idx; LDS atomics).
//              Alignment TMR=16. hb==0 publishes off_al/cnt_al + zeroes
//              xc pad row.
__global__ __launch_bounds__(256) void prep_kernel(const float* __restrict__ W1,
                                                   const float* __restrict__ W2,
                                                   const float* __restrict__ x,
                                                   const int* __restrict__ idx,
                                                   unsigned short* __restrict__ Wt1,
                                                   unsigned short* __restrict__ Wt2,
                                                   unsigned short* __restrict__ xc,
                                                   int* __restrict__ off_al,
                                                   int* __restrict__ cnt_al,
                                                   int* __restrict__ order) {
  const int bid = blockIdx.x;
  const int t = threadIdx.x;
  if (bid < 2688) {
    __shared__ unsigned short Ls[64][72];
    const float* S; unsigned short* Dt; int K, N, Kd, Nd, k0, n0;
    if (bid < 1792) {                    // W1: 16 k-blocks x 7 n-blocks x 16 e
      int e = bid / 112, r = bid % 112;
      k0 = (r % 16) * 64; n0 = (r / 16) * 64;
      S = W1 + (size_t)e * D_K * H_N; Dt = Wt1 + (size_t)e * HP * D_K;
      K = D_K; N = H_N; Kd = D_K; Nd = HP;
    } else {                             // W2: 7 k-blocks x 8 n-blocks x 16 e
      int t2 = bid - 1792; int e = t2 / 56, r = t2 % 56;
      k0 = (r % 7) * 64; n0 = (r / 7) * 64;
      S = W2 + (size_t)e * H_N * K2_N; Dt = Wt2 + (size_t)e * K2_N * HP;
      K = H_N; N = K2_N; Kd = HP; Nd = K2_N;
    }
    const int kk = t >> 4;
    const int nn = (t & 15) * 4;
    float4 v[4];
#pragma unroll
    for (int p = 0; p < 4; ++p) {
      int k = k0 + p * 16 + kk;
      int n = n0 + nn;
      v[p] = make_float4(0.f, 0.f, 0.f, 0.f);
      if (k < K && n + 3 < N) v[p] = *(const float4*)(S + (size_t)k * N + n);
    }
#pragma unroll
    for (int p = 0; p < 4; ++p) {
      Ls[nn + 0][p * 16 + kk] = f2bf(v[p].x);
      Ls[nn + 1][p * 16 + kk] = f2bf(v[p].y);
      Ls[nn + 2][p * 16 + kk] = f2bf(v[p].z);
      Ls[nn + 3][p * 16 + kk] = f2bf(v[p].w);
    }
    __syncthreads();
    const int n2 = t >> 3;
    const int ch = t & 7;
#pragma unroll
    for (int p = 0; p < 2; ++p) {
      int n = n0 + p * 32 + n2;
      int k = k0 + ch * 8;
      if (n < Nd && k < Kd)
        *(uint4*)(Dt + (size_t)n * Kd + k) = *(const uint4*)&Ls[p * 32 + n2][ch * 8];
    }
  } else if (bid < 3200) {
    const int xb = bid - 2688;
    const float* S = x + (size_t)xb * 16 * D_K;
    unsigned short* Dp = xc + (size_t)xb * 16 * D_K;
#pragma unroll
    for (int i = 0; i < 16; ++i) {
      float4 v = *(const float4*)(S + i * D_K + t * 4);
      uint2 o; o.x = pkbf(v.x, v.y); o.y = pkbf(v.z, v.w);
      *(uint2*)(Dp + i * D_K + t * 4) = o;
    }
  } else {
    const int hb = bid - 3200;
    __shared__ int totL[E_N], preL[E_N], offsL[E_N], curL[E_N];
    if (t < E_N) { totL[t] = 0; preL[t] = 0; }
    __syncthreads();
    const int lim = hb * 256;
    for (int i = t; i < B_N; i += 256) {
      const int e0 = idx[i];
      atomicAdd(&totL[e0], 1);
      if (i < lim) atomicAdd(&preL[e0], 1);
    }
    __syncthreads();
    if (t == 0) {
      int acc = 0;
      for (int e = 0; e < E_N; ++e) {
        offsL[e] = acc;
        if (hb == 0) off_al[e] = acc;
        acc += ((totL[e] + TMR - 1) / TMR) * TMR;
      }
      if (hb == 0) off_al[E_N] = acc;
    }
    __syncthreads();
    if (t < E_N) {
      curL[t] = offsL[t] + preL[t];
      if (hb == 0) cnt_al[t] = totL[t];
    }
    __syncthreads();
    const int b = hb * 256 + t;
    const int e = idx[b];
    const int slot = atomicAdd(&curL[e], 1);
    order[slot] = b;
    if (hb == 0) *(uint2*)(xc + (size_t)B_N * D_K + t * 4) = make_uint2(0, 0);
  }
}

// ---------------- mlp: per-block 16-row strip, gemm1 -> LDS h1 -> gemm2 -----
// Round-6 restructure vs round-5 (72us @ 9% occ, 103 barrier-iters):
//  * TMR 32->16: grid 272->528 blocks (~2.06/CU, LDS 67KB -> 2 blocks/CU fit)
//    -> cross-block overlap hides each iteration's vmcnt(0)+barrier drain.
//  * Bs widened to 25 tile slots/buffer: gemm1 = ONE pass of 32 iters
//    (6-7 MFMA/wave/iter), gemm2 = 2 passes of 13 iters -> 58 barrier-iters.
// Verified 32-wide swizzled staging + swapped-operand MFMA reused verbatim.
// h1s row stride 424 shorts (848B) bank-skew; A-frag read from h1s is the
// PLAIN chunk q*8 (staging XOR and read XOR cancel).
__global__ __launch_bounds__(256) void mlp_kernel(
    const unsigned short* __restrict__ xc,
    const unsigned short* __restrict__ Wt1,
    const unsigned short* __restrict__ Wt2,
    const float* __restrict__ b1, const float* __restrict__ b2,
    const int* __restrict__ off_al, const int* __restrict__ cnt_al,
    const int* __restrict__ order, float* __restrict__ out) {
  __shared__ unsigned short h1s[TMR * HPAD];     // 13,568 B
  __shared__ unsigned short Bs[2 * 25 * 512];    // 51,200 B
  __shared__ unsigned short As[2 * 512];         //  2,048 B  (total ~67 KB)
  __shared__ int offs[E_N + 1];
  __shared__ int rowidx[TMR];
  const int t = threadIdx.x;
  // XCD clustering: 528 = 8*66 exact -> bijective; same-expert strips
  // (consecutive vid) stay on one XCD's L2 for weight-panel reuse.
  const int vid = (blockIdx.x & 7) * 66 + (blockIdx.x >> 3);
  const int m0 = vid * TMR;
  if (t <= E_N) offs[t] = off_al[t];
  __syncthreads();
  if (m0 >= offs[E_N]) return;
  int e = 0;
  while (m0 >= offs[e + 1]) ++e;
  if (t < TMR) {
    const bool valid = (m0 + t) < (offs[e] + cnt_al[e]);
    rowidx[t] = valid ? order[m0 + t] : -1;      // pad -> -1
  }
  // zero h1 pad cols [400,424): LDS is uninitialized (could be NaN bits)
  for (int z = t; z < TMR * 12; z += 256) {
    const int row = z / 12, c2 = z % 12;
    *(unsigned int*)&h1s[row * HPAD + 400 + c2 * 2] = 0u;
  }
  __syncthreads();

  const int l = t & 63, w = t >> 6;
  const int r4 = l >> 2;
  const int sgx = (r4 ^ (r4 >> 2)) & 3;
  const int g8 = ((l & 3) ^ sgx) * 8;
  const int ln = l & 15, q = l >> 4;
  const int srx = (ln ^ (ln >> 2)) & 3;
  const int cq = (q ^ srx) * 8;

  const int ar = rowidx[r4];                     // A row for wave-0 staging
  const unsigned short* gA = xc + (size_t)(ar < 0 ? B_N : ar) * D_K + g8;
  const unsigned short* Wt1e = Wt1 + (size_t)e * HP * D_K;
  const unsigned short* Wt2e = Wt2 + (size_t)e * K2_N * HP;

  // ============ gemm1: h1s = relu(gather(xc) @ Wt1^T + b1) ==================
  // ONE pass: 25 tiles; wave w owns tiles {w+4j} (w=0: 7 tiles, else 6).
  {
    const unsigned short* gB[7];
#pragma unroll
    for (int j = 0; j < 7; ++j)
      gB[j] = Wt1e + (size_t)((w + 4 * j) * 16 + r4) * D_K + g8;
    f32x4 acc[7] = {};
    if (w == 0) GLDS(gA, &As[0]);
#pragma unroll
    for (int j = 0; j < 7; ++j)
      if (w + 4 * j < 25) GLDS(gB[j], &Bs[(w + 4 * j) * 512]);
    for (int k0 = 0; k0 < D_K; k0 += 32) {       // 32 iterations
      const int cur = (k0 >> 5) & 1, nxt = cur ^ 1;
      __syncthreads();                            // publishes buf[cur]
      if (k0 + 32 < D_K) {
        if (w == 0) GLDS(gA + k0 + 32, &As[nxt * 512]);
#pragma unroll
        for (int j = 0; j < 7; ++j)
          if (w + 4 * j < 25) GLDS(gB[j] + k0 + 32, &Bs[(nxt * 25 + w + 4 * j) * 512]);
      }
      const bf16x8 af0 = *(const bf16x8*)&As[cur * 512 + ln * 32 + cq];
#pragma unroll
      for (int j = 0; j < 7; ++j)
        if (w + 4 * j < 25) {
          const bf16x8 bf = *(const bf16x8*)&Bs[(cur * 25 + w + 4 * j) * 512 + ln * 32 + cq];
          acc[j] = __builtin_amdgcn_mfma_f32_16x16x32_bf16(bf, af0, acc[j], 0, 0, 0);
        }
    }
    __syncthreads();   // all Bs/As reads done before gemm2 re-stages
    // epilogue: swapped layout -> lane holds m=ln, n=tile*16+4q+reg
#pragma unroll
    for (int j = 0; j < 7; ++j)
      if (w + 4 * j < 25) {
        const int n4 = (w + 4 * j) * 16 + 4 * q;   // <= 396
        const float4 bv = *(const float4*)&b1[e * H_N + n4];
        uint2 o;
        o.x = pkbf(fmaxf(acc[j][0] + bv.x, 0.f), fmaxf(acc[j][1] + bv.y, 0.f));
        o.y = pkbf(fmaxf(acc[j][2] + bv.z, 0.f), fmaxf(acc[j][3] + bv.w, 0.f));
        *(uint2*)&h1s[ln * HPAD + n4] = o;
      }
  }
  // h1s writes published by the first barrier of the gemm2 k-loop.

  // ============ gemm2: out = h1s @ Wt2^T + b2, 32 tiles in 2 passes =========
#pragma unroll 1
  for (int pass = 0; pass < 2; ++pass) {
    const int tstart = pass * 16;
    const unsigned short* gB[4];
#pragma unroll
    for (int j = 0; j < 4; ++j)
      gB[j] = Wt2e + (size_t)((tstart + w + 4 * j) * 16 + r4) * HP + g8;
    f32x4 acc[4] = {};
#pragma unroll
    for (int j = 0; j < 4; ++j)
      GLDS(gB[j], &Bs[(w + 4 * j) * 512]);
    for (int k0 = 0; k0 < HP; k0 += 32) {        // 13 iterations
      const int cur = (k0 >> 5) & 1, nxt = cur ^ 1;
      __syncthreads();
      if (k0 + 32 < HP) {
#pragma unroll
        for (int j = 0; j < 4; ++j)
          GLDS(gB[j] + k0 + 32, &Bs[(nxt * 25 + w + 4 * j) * 512]);
      }
      // A from LDS-resident h1 (plain fragment: chunk q*8, no XOR)
      const bf16x8 af0 = *(const bf16x8*)&h1s[ln * HPAD + k0 + q * 8];
#pragma unroll
      for (int j = 0; j < 4; ++j) {
        const bf16x8 bf = *(const bf16x8*)&Bs[(cur * 25 + w + 4 * j) * 512 + ln * 32 + cq];
        acc[j] = __builtin_amdgcn_mfma_f32_16x16x32_bf16(bf, af0, acc[j], 0, 0, 0);
      }
    }
    __syncthreads();   // protect Bs before next pass re-stages buf0
    // epilogue: scatter float4 rows via rowidx
#pragma unroll
    for (int j = 0; j < 4; ++j) {
      const int n4 = (tstart + w + 4 * j) * 16 + 4 * q;   // < 512
      const float4 bv = *(const float4*)&b2[e * K2_N + n4];
      const int s = rowidx[ln];
      if (s >= 0) {
        float4 v;
        v.x = acc[j][0] + bv.x;
        v.y = acc[j][1] + bv.y;
        v.z = acc[j][2] + bv.z;
        v.w = acc[j][3] + bv.w;
        if (n4 < L_N) *(float4*)&out[(size_t)s * L_N + n4] = v;
        else          *(float4*)&out[(size_t)(B_N + s) * L_N + (n4 - L_N)] = v;
      }
    }
  }
}

extern "C" void kernel_launch(void* const* d_in, const int* in_sizes, int n_in,
                              void* d_out, int out_size, void* d_ws, size_t ws_size,
                              hipStream_t stream) {
  const float* x   = (const float*)d_in[0];
  const int*   idx = (const int*)d_in[1];
  const float* W1  = (const float*)d_in[2];
  const float* b1  = (const float*)d_in[3];
  const float* W2  = (const float*)d_in[4];
  const float* b2  = (const float*)d_in[5];
  float* out = (float*)d_out;

  // ws layout (bytes):
  // off_al@0 (68) | cnt_al@128 (64) | order@2240 (33792 used of 36864)
  // xc@39104 ((8192+1)x1024x2) | Wt1@24,486,080 (16x416x1024x2)
  // Wt2@38,117,568 (16x512x416x2) -> 44,933,312
  char* ws = (char*)d_ws;
  int* off_al = (int*)(ws + 0);
  int* cnt_al = (int*)(ws + 128);
  int* order  = (int*)(ws + 2240);
  unsigned short* xc  = (unsigned short*)(ws + 39104);
  unsigned short* Wt1 = (unsigned short*)(ws + 24486080);
  unsigned short* Wt2 = (unsigned short*)(ws + 38117568);

  prep_kernel<<<3232, 256, 0, stream>>>(W1, W2, x, idx, Wt1, Wt2, xc,
                                        off_al, cnt_al, order);
  mlp_kernel<<<NT2, 256, 0, stream>>>(xc, Wt1, Wt2, b1, b2,
                                      off_al, cnt_al, order, out);
}

// Round 8
// 209.096 us; speedup vs baseline: 1.0586x; 1.0586x over previous
//
#include <hip/hip_runtime.h>
#include <hip/hip_bf16.h>
#include <cstdint>
#include <cstddef>

// Problem constants
#define B_N 8192
#define D_K 1024
#define H_N 400
#define HP  416          // H padded to multiple of 32
#define HPAD 424         // h1 LDS row stride in shorts (bank-skew)
#define K2_N 512
#define E_N 16
#define L_N 256
#define TMR 32                        // rows per block (row-strip)
#define PAD_ROWS (B_N + E_N * TMR)    // 8704
#define NT2 (PAD_ROWS / TMR)          // 272 = 8 XCDs * 34

typedef short bf16x8 __attribute__((ext_vector_type(8)));
typedef float f32x4 __attribute__((ext_vector_type(4)));

// async global->LDS, 16B per lane; LDS dest = wave-uniform base + lane*16.
// Global address may be fully per-lane (gather OK).
#define GLDS(gp, lp) __builtin_amdgcn_global_load_lds( \
    (const __attribute__((address_space(1))) unsigned int*)(gp), \
    (__attribute__((address_space(3))) unsigned int*)(lp), 16, 0, 0)

// Counted-vmcnt pipeline primitives (T3/T4). VMW(N) literal-only.
#define VMW(N) asm volatile("s_waitcnt vmcnt(" #N ")" ::: "memory")
#define SBAR() __builtin_amdgcn_s_barrier()
#define SCHED0() __builtin_amdgcn_sched_barrier(0)

static __device__ __forceinline__ unsigned short f2bf(float f) {
  union { float f; unsigned int u; } c; c.f = f;
  unsigned int u = c.u + 0x7fffu + ((c.u >> 16) & 1u);  // RNE
  return (unsigned short)(u >> 16);
}
static __device__ __forceinline__ unsigned int pkbf(float a, float b) {
  union { __hip_bfloat162 v; unsigned int u; } c;
  c.v = __float22bfloat162_rn(make_float2(a, b));
  return c.u;
}

// ---------------- prep (one launch, fully parallel blocks): ----------------
// [0,1792):    W1 transpose [1024][400] f32 -> [416][1024] bf16 (zero-pad)
// [1792,2688): W2 transpose [400][512] f32 -> [512][416] bf16 (zero-pad)
// [2688,3200): x convert f32 -> bf16 (16 rows/block)
// [3200,3232): scatter (hist self-computed per block from idx; LDS atomics).
//              Alignment TMR=32. hb==0 publishes off_al/cnt_al + zeroes
//              xc pad row.  (verbatim round-5 verified version)
__global__ __launch_bounds__(256) void prep_kernel(const float* __restrict__ W1,
                                                   const float* __restrict__ W2,
                                                   const float* __restrict__ x,
                                                   const int* __restrict__ idx,
                                                   unsigned short* __restrict__ Wt1,
                                                   unsigned short* __restrict__ Wt2,
                                                   unsigned short* __restrict__ xc,
                                                   int* __restrict__ off_al,
                                                   int* __restrict__ cnt_al,
                                                   int* __restrict__ order) {
  const int bid = blockIdx.x;
  const int t = threadIdx.x;
  if (bid < 2688) {
    __shared__ unsigned short Ls[64][72];
    const float* S; unsigned short* Dt; int K, N, Kd, Nd, k0, n0;
    if (bid < 1792) {                    // W1: 16 k-blocks x 7 n-blocks x 16 e
      int e = bid / 112, r = bid % 112;
      k0 = (r % 16) * 64; n0 = (r / 16) * 64;
      S = W1 + (size_t)e * D_K * H_N; Dt = Wt1 + (size_t)e * HP * D_K;
      K = D_K; N = H_N; Kd = D_K; Nd = HP;
    } else {                             // W2: 7 k-blocks x 8 n-blocks x 16 e
      int t2 = bid - 1792; int e = t2 / 56, r = t2 % 56;
      k0 = (r % 7) * 64; n0 = (r / 7) * 64;
      S = W2 + (size_t)e * H_N * K2_N; Dt = Wt2 + (size_t)e * K2_N * HP;
      K = H_N; N = K2_N; Kd = HP; Nd = K2_N;
    }
    const int kk = t >> 4;
    const int nn = (t & 15) * 4;
    float4 v[4];
#pragma unroll
    for (int p = 0; p < 4; ++p) {
      int k = k0 + p * 16 + kk;
      int n = n0 + nn;
      v[p] = make_float4(0.f, 0.f, 0.f, 0.f);
      if (k < K && n + 3 < N) v[p] = *(const float4*)(S + (size_t)k * N + n);
    }
#pragma unroll
    for (int p = 0; p < 4; ++p) {
      Ls[nn + 0][p * 16 + kk] = f2bf(v[p].x);
      Ls[nn + 1][p * 16 + kk] = f2bf(v[p].y);
      Ls[nn + 2][p * 16 + kk] = f2bf(v[p].z);
      Ls[nn + 3][p * 16 + kk] = f2bf(v[p].w);
    }
    __syncthreads();
    const int n2 = t >> 3;
    const int ch = t & 7;
#pragma unroll
    for (int p = 0; p < 2; ++p) {
      int n = n0 + p * 32 + n2;
      int k = k0 + ch * 8;
      if (n < Nd && k < Kd)
        *(uint4*)(Dt + (size_t)n * Kd + k) = *(const uint4*)&Ls[p * 32 + n2][ch * 8];
    }
  } else if (bid < 3200) {
    const int xb = bid - 2688;
    const float* S = x + (size_t)xb * 16 * D_K;
    unsigned short* Dp = xc + (size_t)xb * 16 * D_K;
#pragma unroll
    for (int i = 0; i < 16; ++i) {
      float4 v = *(const float4*)(S + i * D_K + t * 4);
      uint2 o; o.x = pkbf(v.x, v.y); o.y = pkbf(v.z, v.w);
      *(uint2*)(Dp + i * D_K + t * 4) = o;
    }
  } else {
    const int hb = bid - 3200;
    __shared__ int totL[E_N], preL[E_N], offsL[E_N], curL[E_N];
    if (t < E_N) { totL[t] = 0; preL[t] = 0; }
    __syncthreads();
    const int lim = hb * 256;
    for (int i = t; i < B_N; i += 256) {
      const int e0 = idx[i];
      atomicAdd(&totL[e0], 1);
      if (i < lim) atomicAdd(&preL[e0], 1);
    }
    __syncthreads();
    if (t == 0) {
      int acc = 0;
      for (int e = 0; e < E_N; ++e) {
        offsL[e] = acc;
        if (hb == 0) off_al[e] = acc;
        acc += ((totL[e] + TMR - 1) / TMR) * TMR;
      }
      if (hb == 0) off_al[E_N] = acc;
    }
    __syncthreads();
    if (t < E_N) {
      curL[t] = offsL[t] + preL[t];
      if (hb == 0) cnt_al[t] = totL[t];
    }
    __syncthreads();
    const int b = hb * 256 + t;
    const int e = idx[b];
    const int slot = atomicAdd(&curL[e], 1);
    order[slot] = b;
    if (hb == 0) *(uint2*)(xc + (size_t)B_N * D_K + t * 4) = make_uint2(0, 0);
  }
}

// ---------------- mlp: 32-row strip; depth-4 counted-vmcnt pipeline ---------
// Round-7 redesign: round-5/6 showed the 2-buffer vmcnt(0)+barrier loop is
// pure exposed latency at 1 block/CU. This version: at iter i stage slot i+2
// into buf (i+2)&3, wait OWN loads with counted vmcnt (2L steady / L tail / 0
// last), ONE raw s_barrier per iter. WAR: buf (i+2)&3's last reader was iter
// i-2, separated by barrier i-1. RAW: own drain precedes the barrier. vmcnt
// retires in issue order, so any compiler-inserted VMEM only makes waits
// conservative. gemm1 = one 32-iter pass over all 25 tiles (depth-4 Bs);
// gemm2 = 2 passes x 13 iters, uniform L=4. Staging swizzle / swapped-operand
// MFMA / epilogues verbatim from the verified round-5 kernel.
// LDS: STG 110,592 B (g1: As 4x2KB @0 + Bs 4x25x1KB @8KB; g2 reuses @0:
// 4x16x1KB = 64KB) + h1s 27,136 B -> ~135 KB, 1 block/CU by design.
__global__ __launch_bounds__(256, 1) void mlp_kernel(
    const unsigned short* __restrict__ xc,
    const unsigned short* __restrict__ Wt1,
    const unsigned short* __restrict__ Wt2,
    const float* __restrict__ b1, const float* __restrict__ b2,
    const int* __restrict__ off_al, const int* __restrict__ cnt_al,
    const int* __restrict__ order, float* __restrict__ out) {
  __shared__ unsigned short STG[55296];          // 110,592 B (union g1/g2)
  __shared__ unsigned short h1s[TMR * HPAD];     // 27,136 B
  __shared__ int offs[E_N + 1];
  __shared__ int rowidx[TMR];
  const int t = threadIdx.x;
  // XCD clustering: 272 = 8*34 exact bijection.
  const int vid = (blockIdx.x & 7) * 34 + (blockIdx.x >> 3);
  const int m0 = vid * TMR;
  if (t <= E_N) offs[t] = off_al[t];
  __syncthreads();
  if (m0 >= offs[E_N]) return;
  int e = 0;
  while (m0 >= offs[e + 1]) ++e;
  if (t < TMR) {
    const bool valid = (m0 + t) < (offs[e] + cnt_al[e]);
    rowidx[t] = valid ? order[m0 + t] : -1;      // pad -> -1
  }
  // zero h1 pad cols [400,424)
  for (int z = t; z < TMR * 12; z += 256) {
    const int row = z / 12, c2 = z % 12;
    *(unsigned int*)&h1s[row * HPAD + 400 + c2 * 2] = 0u;
  }
  __syncthreads();

  const int l = t & 63, w = t >> 6;
  const int r4 = l >> 2;
  const int sgx = (r4 ^ (r4 >> 2)) & 3;
  const int g8 = ((l & 3) ^ sgx) * 8;
  const int ln = l & 15, q = l >> 4;
  const int srx = (ln ^ (ln >> 2)) & 3;
  const int cq = (q ^ srx) * 8;

  const int ar = (w < 2) ? rowidx[16 * w + r4] : -1;
  const unsigned short* gA = xc + (size_t)(ar < 0 ? B_N : ar) * D_K + g8;
  const unsigned short* Wt1e = Wt1 + (size_t)e * HP * D_K;
  const unsigned short* Wt2e = Wt2 + (size_t)e * K2_N * HP;

  // ============ gemm1: h1s = relu(gather(xc) @ Wt1^T + b1) ==================
  // 25 tiles; wave w owns tiles {w+4j}. Staging L = {A?+B} = {8,7,6,6}.
  {
    const unsigned short* gB1[7];
#pragma unroll
    for (int j = 0; j < 7; ++j)
      gB1[j] = Wt1e + (size_t)((w + 4 * j) * 16 + r4) * D_K + g8;
    f32x4 acc1[7][2] = {};

    auto stage1 = [&](int slot) {
      const int b = slot & 3;
      if (w < 2) GLDS(gA + slot * 32, &STG[b * 1024 + w * 512]);
#pragma unroll
      for (int j = 0; j < 7; ++j)
        if (w + 4 * j < 25)
          GLDS(gB1[j] + slot * 32, &STG[4096 + (b * 25 + w + 4 * j) * 512]);
    };

    stage1(0); stage1(1);
#pragma unroll 1
    for (int i = 0; i < 32; ++i) {
      const int cb = i & 3;
      if (i + 2 < 32) stage1(i + 2);
      if (i < 30)      { if (w == 0) VMW(16); else if (w == 1) VMW(14); else VMW(12); }
      else if (i == 30){ if (w == 0) VMW(8);  else if (w == 1) VMW(7);  else VMW(6); }
      else             VMW(0);
      SBAR(); SCHED0();
      const bf16x8 af0 = *(const bf16x8*)&STG[cb * 1024 + ln * 32 + cq];
      const bf16x8 af1 = *(const bf16x8*)&STG[cb * 1024 + 512 + ln * 32 + cq];
#pragma unroll
      for (int j = 0; j < 7; ++j)
        if (w + 4 * j < 25) {
          const bf16x8 bf = *(const bf16x8*)&STG[4096 + (cb * 25 + w + 4 * j) * 512 + ln * 32 + cq];
          acc1[j][0] = __builtin_amdgcn_mfma_f32_16x16x32_bf16(bf, af0, acc1[j][0], 0, 0, 0);
          acc1[j][1] = __builtin_amdgcn_mfma_f32_16x16x32_bf16(bf, af1, acc1[j][1], 0, 0, 0);
        }
    }
    // epilogue: swapped layout -> lane holds m=16i+ln, n=tile*16+4q+reg
#pragma unroll
    for (int j = 0; j < 7; ++j)
      if (w + 4 * j < 25) {
        const int n4 = (w + 4 * j) * 16 + 4 * q;   // <= 396
        const float4 bv = *(const float4*)&b1[e * H_N + n4];
#pragma unroll
        for (int i = 0; i < 2; ++i) {
          const int m = 16 * i + ln;
          uint2 o;
          o.x = pkbf(fmaxf(acc1[j][i][0] + bv.x, 0.f), fmaxf(acc1[j][i][1] + bv.y, 0.f));
          o.y = pkbf(fmaxf(acc1[j][i][2] + bv.z, 0.f), fmaxf(acc1[j][i][3] + bv.w, 0.f));
          *(uint2*)&h1s[m * HPAD + n4] = o;
        }
      }
  }
  // transition: drain h1s ds_writes, close all STG reads, publish h1s.
  asm volatile("s_waitcnt lgkmcnt(0)" ::: "memory");
  SBAR(); SCHED0();

  // ============ gemm2: out = h1s @ Wt2^T + b2, 32 tiles in 2 passes =========
#pragma unroll 1
  for (int p = 0; p < 2; ++p) {
    const unsigned short* gB2[4];
#pragma unroll
    for (int j = 0; j < 4; ++j)
      gB2[j] = Wt2e + (size_t)((p * 16 + w + 4 * j) * 16 + r4) * HP + g8;
    f32x4 acc2[4][2] = {};

    auto stage2 = [&](int slot) {
      const int b = slot & 3;
#pragma unroll
      for (int j = 0; j < 4; ++j)
        GLDS(gB2[j] + slot * 32, &STG[(b * 16 + w + 4 * j) * 512]);
    };

    stage2(0); stage2(1);
#pragma unroll 1
    for (int i = 0; i < 13; ++i) {
      const int cb = i & 3;
      if (i + 2 < 13) stage2(i + 2);
      if (i < 11)      VMW(8);
      else if (i == 11) VMW(4);
      else             VMW(0);
      SBAR(); SCHED0();
      const bf16x8 a0 = *(const bf16x8*)&h1s[ln * HPAD + i * 32 + q * 8];
      const bf16x8 a1 = *(const bf16x8*)&h1s[(16 + ln) * HPAD + i * 32 + q * 8];
#pragma unroll
      for (int j = 0; j < 4; ++j) {
        const bf16x8 bf = *(const bf16x8*)&STG[(cb * 16 + w + 4 * j) * 512 + ln * 32 + cq];
        acc2[j][0] = __builtin_amdgcn_mfma_f32_16x16x32_bf16(bf, a0, acc2[j][0], 0, 0, 0);
        acc2[j][1] = __builtin_amdgcn_mfma_f32_16x16x32_bf16(bf, a1, acc2[j][1], 0, 0, 0);
      }
    }
    // epilogue: scatter float4 rows via rowidx
#pragma unroll
    for (int j = 0; j < 4; ++j) {
      const int n4 = (p * 16 + w + 4 * j) * 16 + 4 * q;   // < 512
      const float4 bv = *(const float4*)&b2[e * K2_N + n4];
#pragma unroll
      for (int i = 0; i < 2; ++i) {
        const int s = rowidx[16 * i + ln];
        if (s >= 0) {
          float4 v;
          v.x = acc2[j][i][0] + bv.x;
          v.y = acc2[j][i][1] + bv.y;
          v.z = acc2[j][i][2] + bv.z;
          v.w = acc2[j][i][3] + bv.w;
          if (n4 < L_N) *(float4*)&out[(size_t)s * L_N + n4] = v;
          else          *(float4*)&out[(size_t)(B_N + s) * L_N + (n4 - L_N)] = v;
        }
      }
    }
    if (p == 0) { SBAR(); }   // close pass-0 STG reads before pass-1 staging
  }
}

extern "C" void kernel_launch(void* const* d_in, const int* in_sizes, int n_in,
                              void* d_out, int out_size, void* d_ws, size_t ws_size,
                              hipStream_t stream) {
  const float* x   = (const float*)d_in[0];
  const int*   idx = (const int*)d_in[1];
  const float* W1  = (const float*)d_in[2];
  const float* b1  = (const float*)d_in[3];
  const float* W2  = (const float*)d_in[4];
  const float* b2  = (const float*)d_in[5];
  float* out = (float*)d_out;

  // ws layout (bytes):
  // off_al@0 (68) | cnt_al@128 (64) | order@2240 (34816 used of 36864)
  // xc@39104 ((8192+1)x1024x2) | Wt1@24,486,080 (16x416x1024x2)
  // Wt2@38,117,568 (16x512x416x2) -> 44,933,312
  char* ws = (char*)d_ws;
  int* off_al = (int*)(ws + 0);
  int* cnt_al = (int*)(ws + 128);
  int* order  = (int*)(ws + 2240);
  unsigned short* xc  = (unsigned short*)(ws + 39104);
  unsigned short* Wt1 = (unsigned short*)(ws + 24486080);
  unsigned short* Wt2 = (unsigned short*)(ws + 38117568);

  prep_kernel<<<3232, 256, 0, stream>>>(W1, W2, x, idx, Wt1, Wt2, xc,
                                        off_al, cnt_al, order);
  mlp_kernel<<<NT2, 256, 0, stream>>>(xc, Wt1, Wt2, b1, b2,
                                      off_al, cnt_al, order, out);
}

// Round 9
// 163.384 us; speedup vs baseline: 1.3548x; 1.2798x over previous
//
#include <hip/hip_runtime.h>
#include <hip/hip_bf16.h>
#include <cstdint>
#include <cstddef>

// Problem constants
#define B_N 8192
#define D_K 1024
#define H_N 400
#define HP  416          // H padded to multiple of 32
#define K2_N 512
#define E_N 16
#define L_N 256
#define TM 64
#define PAD_ROWS (B_N + E_N * TM)   // 9216
#define NTILES (PAD_ROWS / TM)      // 144

typedef short bf16x8 __attribute__((ext_vector_type(8)));
typedef float f32x4 __attribute__((ext_vector_type(4)));

// async global->LDS, 16B per lane; LDS dest = wave-uniform base + lane*16.
// Global address may be fully per-lane (gather OK).
#define GLDS(gp, lp) __builtin_amdgcn_global_load_lds( \
    (const __attribute__((address_space(1))) unsigned int*)(gp), \
    (__attribute__((address_space(3))) unsigned int*)(lp), 16, 0, 0)

// Counted-vmcnt pipeline primitives (T3/T4). VMW(N) literal-only.
#define VMW(N) asm volatile("s_waitcnt vmcnt(" #N ")" ::: "memory")
#define LGKM0() asm volatile("s_waitcnt lgkmcnt(0)" ::: "memory")
#define SBAR() __builtin_amdgcn_s_barrier()
#define SCHED0() __builtin_amdgcn_sched_barrier(0)

static __device__ __forceinline__ unsigned short f2bf(float f) {
  union { float f; unsigned int u; } c; c.f = f;
  unsigned int u = c.u + 0x7fffu + ((c.u >> 16) & 1u);  // RNE
  return (unsigned short)(u >> 16);
}
static __device__ __forceinline__ unsigned int pkbf(float a, float b) {
  union { __hip_bfloat162 v; unsigned int u; } c;
  c.v = __float22bfloat162_rn(make_float2(a, b));
  return c.u;
}

// ---------------- prep (one launch, fully parallel blocks): ----------------
// (verbatim round-3 verified version, TM=64 alignment)
__global__ __launch_bounds__(256) void prep_kernel(const float* __restrict__ W1,
                                                   const float* __restrict__ W2,
                                                   const float* __restrict__ x,
                                                   const int* __restrict__ idx,
                                                   unsigned short* __restrict__ Wt1,
                                                   unsigned short* __restrict__ Wt2,
                                                   unsigned short* __restrict__ xc,
                                                   int* __restrict__ off_al,
                                                   int* __restrict__ cnt_al,
                                                   int* __restrict__ order) {
  const int bid = blockIdx.x;
  const int t = threadIdx.x;
  if (bid < 2688) {
    __shared__ unsigned short Ls[64][72];
    const float* S; unsigned short* Dt; int K, N, Kd, Nd, k0, n0;
    if (bid < 1792) {                    // W1: 16 k-blocks x 7 n-blocks x 16 e
      int e = bid / 112, r = bid % 112;
      k0 = (r % 16) * 64; n0 = (r / 16) * 64;
      S = W1 + (size_t)e * D_K * H_N; Dt = Wt1 + (size_t)e * HP * D_K;
      K = D_K; N = H_N; Kd = D_K; Nd = HP;
    } else {                             // W2: 7 k-blocks x 8 n-blocks x 16 e
      int t2 = bid - 1792; int e = t2 / 56, r = t2 % 56;
      k0 = (r % 7) * 64; n0 = (r / 7) * 64;
      S = W2 + (size_t)e * H_N * K2_N; Dt = Wt2 + (size_t)e * K2_N * HP;
      K = H_N; N = K2_N; Kd = HP; Nd = K2_N;
    }
    const int kk = t >> 4;
    const int nn = (t & 15) * 4;
    float4 v[4];
#pragma unroll
    for (int p = 0; p < 4; ++p) {
      int k = k0 + p * 16 + kk;
      int n = n0 + nn;
      v[p] = make_float4(0.f, 0.f, 0.f, 0.f);
      if (k < K && n + 3 < N) v[p] = *(const float4*)(S + (size_t)k * N + n);
    }
#pragma unroll
    for (int p = 0; p < 4; ++p) {
      Ls[nn + 0][p * 16 + kk] = f2bf(v[p].x);
      Ls[nn + 1][p * 16 + kk] = f2bf(v[p].y);
      Ls[nn + 2][p * 16 + kk] = f2bf(v[p].z);
      Ls[nn + 3][p * 16 + kk] = f2bf(v[p].w);
    }
    __syncthreads();
    const int n2 = t >> 3;
    const int ch = t & 7;
#pragma unroll
    for (int p = 0; p < 2; ++p) {
      int n = n0 + p * 32 + n2;
      int k = k0 + ch * 8;
      if (n < Nd && k < Kd)
        *(uint4*)(Dt + (size_t)n * Kd + k) = *(const uint4*)&Ls[p * 32 + n2][ch * 8];
    }
  } else if (bid < 3200) {
    const int xb = bid - 2688;
    const float* S = x + (size_t)xb * 16 * D_K;
    unsigned short* Dp = xc + (size_t)xb * 16 * D_K;
#pragma unroll
    for (int i = 0; i < 16; ++i) {
      float4 v = *(const float4*)(S + i * D_K + t * 4);
      uint2 o; o.x = pkbf(v.x, v.y); o.y = pkbf(v.z, v.w);
      *(uint2*)(Dp + i * D_K + t * 4) = o;
    }
  } else {
    const int hb = bid - 3200;
    __shared__ int totL[E_N], preL[E_N], offsL[E_N], curL[E_N];
    if (t < E_N) { totL[t] = 0; preL[t] = 0; }
    __syncthreads();
    const int lim = hb * 256;
    for (int i = t; i < B_N; i += 256) {
      const int e0 = idx[i];
      atomicAdd(&totL[e0], 1);
      if (i < lim) atomicAdd(&preL[e0], 1);
    }
    __syncthreads();
    if (t == 0) {
      int acc = 0;
      for (int e = 0; e < E_N; ++e) {
        offsL[e] = acc;
        if (hb == 0) off_al[e] = acc;
        acc += ((totL[e] + TM - 1) / TM) * TM;
      }
      if (hb == 0) off_al[E_N] = acc;
    }
    __syncthreads();
    if (t < E_N) {
      curL[t] = offsL[t] + preL[t];
      if (hb == 0) cnt_al[t] = totL[t];
    }
    __syncthreads();
    const int b = hb * 256 + t;
    const int e = idx[b];
    const int slot = atomicAdd(&curL[e], 1);
    order[slot] = b;
    if (hb == 0) *(uint2*)(xc + (size_t)B_N * D_K + t * 4) = make_uint2(0, 0);
  }
}

// XCD-clustering swizzle (verbatim round 3): 576 wgs, 8 XCDs, 72/XCD.
static __device__ __forceinline__ void swz_decode(int bx, int by, int& mt, int& nb) {
  const int L = bx + NTILES * by;          // 0..575
  const int vid = (L & 7) * 72 + (L >> 3);
  mt = vid >> 2;
  nb = vid & 3;
}

// ---------------- GEMM1: depth-4 counted-vmcnt pipeline ---------------------
// Same memory layout/addressing as the verified round-3 kernel, but the
// K-loop is 32 x BK=32 slots with stage-ahead-2 and counted vmcnt:
//   iter i: stage slot i+2 (own L loads) -> VMW(2L) (slot i's OWN loads
//   retired) -> lgkmcnt(0) (prev iter's ds_reads drained: WAR airtight,
//   slot reuse is 4 iters away with a barrier in between) -> s_barrier
//   (all waves' slot-i loads retired since each passed its own VMW) -> MFMA.
// No vmcnt(0) anywhere in the loop. 48 KB LDS -> 3 blocks/CU preserved
// (12 waves/CU TLP on top of the in-wave pipeline).
__global__ __launch_bounds__(256) void gemm1_kernel(const unsigned short* __restrict__ xc,
                                                    const unsigned short* __restrict__ Wt1,
                                                    const float* __restrict__ b1,
                                                    const int* __restrict__ off_al,
                                                    const int* __restrict__ cnt_al,
                                                    const int* __restrict__ order,
                                                    unsigned short* __restrict__ h1buf) {
  __shared__ unsigned short As[4][64 * 32];    // 16 KB
  __shared__ unsigned short Bs[4][128 * 32];   // 32 KB
  __shared__ int offs[E_N + 1];
  __shared__ int rowidx[TM];
  const int tid = threadIdx.x;
  int mt, nb;
  swz_decode(blockIdx.x, blockIdx.y, mt, nb);
  const int m0 = mt * TM;
  if (tid <= E_N) offs[tid] = off_al[tid];
  __syncthreads();
  if (m0 >= offs[E_N]) return;
  int e = 0;
  while (m0 >= offs[e + 1]) ++e;
  if (tid < TM) {
    const bool valid = (m0 + tid) < (offs[e] + cnt_al[e]);
    rowidx[tid] = valid ? order[m0 + tid] : B_N;   // pad -> zero row
  }
  __syncthreads();
  const unsigned short* Wt1e = Wt1 + (size_t)e * HP * D_K;

  const int l = tid & 63, w = tid >> 6;
  const int r4 = l >> 2;
  const int sg = (r4 ^ (r4 >> 2)) & 3;
  const int g8 = ((l & 3) ^ sg) * 8;
  const int t0 = nb * 8 + 2 * w;            // first of two 16-col tiles (0..24)
  const bool act0 = (t0 < 25);
  const bool act1 = (t0 + 1 < 25);
  const int Lw = 1 + (act0 ? 1 : 0) + (act1 ? 1 : 0);   // own loads per slot
  const unsigned short* gA = xc + (size_t)rowidx[16 * w + r4] * D_K + g8;
  const unsigned short* gB0 = Wt1e + (size_t)(t0 * 16 + r4) * D_K + g8;
  const unsigned short* gB1 = gB0 + (size_t)16 * D_K;

  const int ln = l & 15, q = l >> 4;
  const int sr = (ln ^ (ln >> 2)) & 3;
  const int cq = (q ^ sr) * 8;

  f32x4 acc[4][2] = {};

  auto stage = [&](int slot) {
    const int b = slot & 3;
    GLDS(gA + slot * 32, &As[b][16 * w * 32]);
    if (act0) GLDS(gB0 + slot * 32, &Bs[b][(2 * w + 0) * 512]);
    if (act1) GLDS(gB1 + slot * 32, &Bs[b][(2 * w + 1) * 512]);
  };

  stage(0); stage(1);
#pragma unroll 1
  for (int i = 0; i < 32; ++i) {
    const int cb = i & 3;
    if (i + 2 < 32) stage(i + 2);
    if (i < 30)       { if (Lw == 3) VMW(6); else if (Lw == 2) VMW(4); else VMW(2); }
    else if (i == 30) { if (Lw == 3) VMW(3); else if (Lw == 2) VMW(2); else VMW(1); }
    else              VMW(0);
    LGKM0();
    SBAR(); SCHED0();
    if (act0) {
      bf16x8 af[4];
#pragma unroll
      for (int i4 = 0; i4 < 4; ++i4)
        af[i4] = *(const bf16x8*)&As[cb][(16 * i4 + ln) * 32 + cq];
      bf16x8 b0f = *(const bf16x8*)&Bs[cb][(2 * w + 0) * 512 + ln * 32 + cq];
#pragma unroll
      for (int i4 = 0; i4 < 4; ++i4)
        acc[i4][0] = __builtin_amdgcn_mfma_f32_16x16x32_bf16(b0f, af[i4], acc[i4][0], 0, 0, 0);
      if (act1) {
        bf16x8 b1f = *(const bf16x8*)&Bs[cb][(2 * w + 1) * 512 + ln * 32 + cq];
#pragma unroll
        for (int i4 = 0; i4 < 4; ++i4)
          acc[i4][1] = __builtin_amdgcn_mfma_f32_16x16x32_bf16(b1f, af[i4], acc[i4][1], 0, 0, 0);
      }
    }
  }

  // epilogue (verbatim round 3): lane holds m = m0+16i+ln, n = tile*16+4q+reg.
#pragma unroll
  for (int j = 0; j < 2; ++j) {
    if (j == 0 ? act0 : act1) {
      const int n4 = (t0 + j) * 16 + 4 * q;          // always < 400
      const float4 bv = *(const float4*)&b1[e * H_N + n4];
#pragma unroll
      for (int i = 0; i < 4; ++i) {
        const size_t m = (size_t)(m0 + 16 * i + ln);
        uint2 o;
        o.x = pkbf(fmaxf(acc[i][j][0] + bv.x, 0.f), fmaxf(acc[i][j][1] + bv.y, 0.f));
        o.y = pkbf(fmaxf(acc[i][j][2] + bv.z, 0.f), fmaxf(acc[i][j][3] + bv.w, 0.f));
        *(uint2*)&h1buf[m * HP + n4] = o;
      }
    }
  }
  // h1 pad cols [400,416) stay unwritten: Wt2 rows there are zero.
}

// ---------------- GEMM2: depth-4 counted-vmcnt pipeline ---------------------
// K=416 -> 13 slots of 32; L=3 uniform. Epilogue verbatim round 3.
__global__ __launch_bounds__(256) void gemm2_kernel(const unsigned short* __restrict__ h1buf,
                                                    const unsigned short* __restrict__ Wt2,
                                                    const float* __restrict__ b2,
                                                    const int* __restrict__ off_al,
                                                    const int* __restrict__ cnt_al,
                                                    const int* __restrict__ order,
                                                    float* __restrict__ out) {
  __shared__ unsigned short As[4][64 * 32];
  __shared__ unsigned short Bs[4][128 * 32];
  __shared__ int offs[E_N + 1];
  __shared__ int rowidx[TM];
  const int tid = threadIdx.x;
  int mt, nb;
  swz_decode(blockIdx.x, blockIdx.y, mt, nb);
  const int m0 = mt * TM;
  if (tid <= E_N) offs[tid] = off_al[tid];
  __syncthreads();
  if (m0 >= offs[E_N]) return;
  int e = 0;
  while (m0 >= offs[e + 1]) ++e;
  if (tid < TM) {
    const bool valid = (m0 + tid) < (offs[e] + cnt_al[e]);
    rowidx[tid] = valid ? order[m0 + tid] : -1;
  }
  __syncthreads();
  const unsigned short* Wt2e = Wt2 + (size_t)e * K2_N * HP;

  const int l = tid & 63, w = tid >> 6;
  const int r4 = l >> 2;
  const int sg = (r4 ^ (r4 >> 2)) & 3;
  const int g8 = ((l & 3) ^ sg) * 8;
  const int t0 = nb * 8 + 2 * w;            // two 16-col tiles of 32 (exact)
  const unsigned short* gA = h1buf + (size_t)(m0 + 16 * w + r4) * HP + g8;
  const unsigned short* gB0 = Wt2e + (size_t)(t0 * 16 + r4) * HP + g8;
  const unsigned short* gB1 = gB0 + (size_t)16 * HP;

  const int ln = l & 15, q = l >> 4;
  const int sr = (ln ^ (ln >> 2)) & 3;
  const int cq = (q ^ sr) * 8;

  f32x4 acc[4][2] = {};

  auto stage = [&](int slot) {
    const int b = slot & 3;
    GLDS(gA + slot * 32, &As[b][16 * w * 32]);
    GLDS(gB0 + slot * 32, &Bs[b][(2 * w + 0) * 512]);
    GLDS(gB1 + slot * 32, &Bs[b][(2 * w + 1) * 512]);
  };

  stage(0); stage(1);
#pragma unroll 1
  for (int i = 0; i < 13; ++i) {
    const int cb = i & 3;
    if (i + 2 < 13) stage(i + 2);
    if (i < 11)       VMW(6);
    else if (i == 11) VMW(3);
    else              VMW(0);
    LGKM0();
    SBAR(); SCHED0();
    bf16x8 af[4];
#pragma unroll
    for (int i4 = 0; i4 < 4; ++i4)
      af[i4] = *(const bf16x8*)&As[cb][(16 * i4 + ln) * 32 + cq];
    bf16x8 b0f = *(const bf16x8*)&Bs[cb][(2 * w + 0) * 512 + ln * 32 + cq];
#pragma unroll
    for (int i4 = 0; i4 < 4; ++i4)
      acc[i4][0] = __builtin_amdgcn_mfma_f32_16x16x32_bf16(b0f, af[i4], acc[i4][0], 0, 0, 0);
    bf16x8 b1f = *(const bf16x8*)&Bs[cb][(2 * w + 1) * 512 + ln * 32 + cq];
#pragma unroll
    for (int i4 = 0; i4 < 4; ++i4)
      acc[i4][1] = __builtin_amdgcn_mfma_f32_16x16x32_bf16(b1f, af[i4], acc[i4][1], 0, 0, 0);
  }

  // epilogue (verbatim round 3): scatter float4 rows via rowidx.
#pragma unroll
  for (int j = 0; j < 2; ++j) {
    const int n4 = (t0 + j) * 16 + 4 * q;
    const float4 bv = *(const float4*)&b2[e * K2_N + n4];
#pragma unroll
    for (int i = 0; i < 4; ++i) {
      const int s = rowidx[16 * i + 4 * q + 0 * 0 + (0)];
      (void)s;
      const int s2 = rowidx[16 * i + ln];
      if (s2 >= 0) {
        float4 v;
        v.x = acc[i][j][0] + bv.x;
        v.y = acc[i][j][1] + bv.y;
        v.z = acc[i][j][2] + bv.z;
        v.w = acc[i][j][3] + bv.w;
        if (n4 < L_N) *(float4*)&out[(size_t)s2 * L_N + n4] = v;
        else          *(float4*)&out[(size_t)(B_N + s2) * L_N + (n4 - L_N)] = v;
      }
    }
  }
}

extern "C" void kernel_launch(void* const* d_in, const int* in_sizes, int n_in,
                              void* d_out, int out_size, void* d_ws, size_t ws_size,
                              hipStream_t stream) {
  const float* x   = (const float*)d_in[0];
  const int*   idx = (const int*)d_in[1];
  const float* W1  = (const float*)d_in[2];
  const float* b1  = (const float*)d_in[3];
  const float* W2  = (const float*)d_in[4];
  const float* b2  = (const float*)d_in[5];
  float* out = (float*)d_out;

  // ws layout (bytes), total ~44.9 MB (round-3 map):
  // off_al@0 (68) | cnt_al@128 (64) | order@2240 (36864)
  // xc@39104 ((8192+1)x1024x2) | h1@16,818,368 (9216x416x2)
  // Wt1@24,486,080 (16x416x1024x2) | Wt2@38,117,568 (16x512x416x2)
  char* ws = (char*)d_ws;
  int* off_al = (int*)(ws + 0);
  int* cnt_al = (int*)(ws + 128);
  int* order  = (int*)(ws + 2240);
  unsigned short* xc  = (unsigned short*)(ws + 39104);
  unsigned short* h1  = (unsigned short*)(ws + 16818368);
  unsigned short* Wt1 = (unsigned short*)(ws + 24486080);
  unsigned short* Wt2 = (unsigned short*)(ws + 38117568);

  prep_kernel<<<3232, 256, 0, stream>>>(W1, W2, x, idx, Wt1, Wt2, xc,
                                        off_al, cnt_al, order);
  gemm1_kernel<<<dim3(NTILES, 4), 256, 0, stream>>>(xc, Wt1, b1, off_al, cnt_al, order, h1);
  gemm2_kernel<<<dim3(NTILES, 4), 256, 0, stream>>>(h1, Wt2, b2, off_al, cnt_al, order, out);
}

// Round 10
// 158.601 us; speedup vs baseline: 1.3957x; 1.0302x over previous
//
#include <hip/hip_runtime.h>
#include <hip/hip_bf16.h>
#include <cstdint>
#include <cstddef>

// Problem constants
#define B_N 8192
#define D_K 1024
#define H_N 400
#define HP  416          // H padded to multiple of 32
#define K2_N 512
#define E_N 16
#define L_N 256
#define TM 64
#define PAD_ROWS (B_N + E_N * TM)   // 9216
#define NTILES (PAD_ROWS / TM)      // 144

typedef short bf16x8 __attribute__((ext_vector_type(8)));
typedef float f32x4 __attribute__((ext_vector_type(4)));

// async global->LDS, 16B per lane; LDS dest = wave-uniform base + lane*16.
// Global address may be fully per-lane (gather OK).
#define GLDS(gp, lp) __builtin_amdgcn_global_load_lds( \
    (const __attribute__((address_space(1))) unsigned int*)(gp), \
    (__attribute__((address_space(3))) unsigned int*)(lp), 16, 0, 0)

static __device__ __forceinline__ unsigned short f2bf(float f) {
  union { float f; unsigned int u; } c; c.f = f;
  unsigned int u = c.u + 0x7fffu + ((c.u >> 16) & 1u);  // RNE
  return (unsigned short)(u >> 16);
}
static __device__ __forceinline__ unsigned int pkbf(float a, float b) {
  union { __hip_bfloat162 v; unsigned int u; } c;
  c.v = __float22bfloat162_rn(make_float2(a, b));
  return c.u;
}

// ---------------- prep (one launch, fully parallel blocks): ----------------
// Unit order (round-9: longest-first so the slow scatter blocks OVERLAP the
// streaming work instead of extending the makespan tail):
// [0,32):      scatter: block hb places samples [hb*256,hb*256+256).
//              Histogram self-computed from idx with PER-WAVE sub-histograms
//              (4x16: waves don't contend) and wave-uniform chunk test c<hb
//              (lim=hb*256 -> whole chunks only). hb==0 publishes
//              off_al/cnt_al + zeroes xc pad row.
// [32,1824):   W1 transpose [1024][400] f32 -> [416][1024] bf16 (zero-pad)
// [1824,2720): W2 transpose [400][512] f32 -> [512][416] bf16 (zero-pad)
// [2720,3232): x convert f32 -> bf16 (16 rows/block)
__global__ __launch_bounds__(256) void prep_kernel(const float* __restrict__ W1,
                                                   const float* __restrict__ W2,
                                                   const float* __restrict__ x,
                                                   const int* __restrict__ idx,
                                                   unsigned short* __restrict__ Wt1,
                                                   unsigned short* __restrict__ Wt2,
                                                   unsigned short* __restrict__ xc,
                                                   int* __restrict__ off_al,
                                                   int* __restrict__ cnt_al,
                                                   int* __restrict__ order) {
  const int bid = blockIdx.x;
  const int t = threadIdx.x;
  if (bid < 32) {
    const int hb = bid;
    __shared__ int totW[4][E_N], preW[4][E_N];
    __shared__ int totL[E_N], preL[E_N], offsL[E_N], curL[E_N];
    const int wv = t >> 6;
    if (t < 64) { totW[t >> 4][t & 15] = 0; preW[t >> 4][t & 15] = 0; }
    __syncthreads();
#pragma unroll 1
    for (int c = 0; c < 32; ++c) {
      const int e0 = idx[c * 256 + t];
      atomicAdd(&totW[wv][e0], 1);
      if (c < hb) atomicAdd(&preW[wv][e0], 1);   // wave-uniform branch
    }
    __syncthreads();
    if (t < E_N) {
      totL[t] = totW[0][t] + totW[1][t] + totW[2][t] + totW[3][t];
      preL[t] = preW[0][t] + preW[1][t] + preW[2][t] + preW[3][t];
    }
    __syncthreads();
    if (t == 0) {
      int acc = 0;
      for (int e = 0; e < E_N; ++e) {
        offsL[e] = acc;
        if (hb == 0) off_al[e] = acc;
        acc += ((totL[e] + TM - 1) / TM) * TM;
      }
      if (hb == 0) off_al[E_N] = acc;
    }
    __syncthreads();
    if (t < E_N) {
      curL[t] = offsL[t] + preL[t];
      if (hb == 0) cnt_al[t] = totL[t];
    }
    __syncthreads();
    const int b = hb * 256 + t;
    const int e = idx[b];
    const int slot = atomicAdd(&curL[e], 1);
    order[slot] = b;
    if (hb == 0) *(uint2*)(xc + (size_t)B_N * D_K + t * 4) = make_uint2(0, 0);
  } else if (bid < 2720) {
    const int u = bid - 32;
    __shared__ unsigned short Ls[64][72];
    const float* S; unsigned short* Dt; int K, N, Kd, Nd, k0, n0;
    if (u < 1792) {                      // W1: 16 k-blocks x 7 n-blocks x 16 e
      int e = u / 112, r = u % 112;
      k0 = (r % 16) * 64; n0 = (r / 16) * 64;
      S = W1 + (size_t)e * D_K * H_N; Dt = Wt1 + (size_t)e * HP * D_K;
      K = D_K; N = H_N; Kd = D_K; Nd = HP;
    } else {                             // W2: 7 k-blocks x 8 n-blocks x 16 e
      int t2 = u - 1792; int e = t2 / 56, r = t2 % 56;
      k0 = (r % 7) * 64; n0 = (r / 7) * 64;
      S = W2 + (size_t)e * H_N * K2_N; Dt = Wt2 + (size_t)e * K2_N * HP;
      K = H_N; N = K2_N; Kd = HP; Nd = K2_N;
    }
    const int kk = t >> 4;
    const int nn = (t & 15) * 4;
    float4 v[4];
#pragma unroll
    for (int p = 0; p < 4; ++p) {
      int k = k0 + p * 16 + kk;
      int n = n0 + nn;
      v[p] = make_float4(0.f, 0.f, 0.f, 0.f);
      if (k < K && n + 3 < N) v[p] = *(const float4*)(S + (size_t)k * N + n);
    }
#pragma unroll
    for (int p = 0; p < 4; ++p) {
      Ls[nn + 0][p * 16 + kk] = f2bf(v[p].x);
      Ls[nn + 1][p * 16 + kk] = f2bf(v[p].y);
      Ls[nn + 2][p * 16 + kk] = f2bf(v[p].z);
      Ls[nn + 3][p * 16 + kk] = f2bf(v[p].w);
    }
    __syncthreads();
    const int n2 = t >> 3;
    const int ch = t & 7;
#pragma unroll
    for (int p = 0; p < 2; ++p) {
      int n = n0 + p * 32 + n2;
      int k = k0 + ch * 8;
      if (n < Nd && k < Kd)
        *(uint4*)(Dt + (size_t)n * Kd + k) = *(const uint4*)&Ls[p * 32 + n2][ch * 8];
    }
  } else {
    const int xb = bid - 2720;
    const float* S = x + (size_t)xb * 16 * D_K;
    unsigned short* Dp = xc + (size_t)xb * 16 * D_K;
#pragma unroll
    for (int i = 0; i < 16; ++i) {
      float4 v = *(const float4*)(S + i * D_K + t * 4);
      uint2 o; o.x = pkbf(v.x, v.y); o.y = pkbf(v.z, v.w);
      *(uint2*)(Dp + i * D_K + t * 4) = o;
    }
  }
}

// XCD-clustering swizzle for the GEMM grids (576 wgs, 8 XCDs, 72/XCD):
// linear dispatch id L -> vid = (L%8)*72 + L/8 (bijective), decode
// mt = vid>>2 (m-tile), nb = vid&3 (n-chunk).
static __device__ __forceinline__ void swz_decode(int bx, int by, int& mt, int& nb) {
  const int L = bx + NTILES * by;          // 0..575
  const int vid = (L & 7) * 72 + (L >> 3);
  mt = vid >> 2;
  nb = vid & 3;
}

// ---------------- GEMM1 (byte-exact best-measured R2 config) ----------------
// grid (144,4) swizzled; two 16-col tiles/wave; BK=64 K-step of two 32-wide
// swizzled sub-tiles (16 iters). Swapped MFMA operands -> packed bf16x4
// stores. A rows DMA-gathered via order (pad -> zero row B_N).
__global__ __launch_bounds__(256) void gemm1_kernel(const unsigned short* __restrict__ xc,
                                                    const unsigned short* __restrict__ Wt1,
                                                    const float* __restrict__ b1,
                                                    const int* __restrict__ off_al,
                                                    const int* __restrict__ cnt_al,
                                                    const int* __restrict__ order,
                                                    unsigned short* __restrict__ h1buf) {
  __shared__ unsigned short As[2 * 2 * 2048];   // [buf][ksub][64*32]  16 KB
  __shared__ unsigned short Bs[2 * 2 * 4096];   // [buf][ksub][128*32] 32 KB
  __shared__ int offs[E_N + 1];
  __shared__ int rowidx[TM];
  const int tid = threadIdx.x;
  int mt, nb;
  swz_decode(blockIdx.x, blockIdx.y, mt, nb);
  const int m0 = mt * TM;
  if (tid <= E_N) offs[tid] = off_al[tid];
  __syncthreads();
  if (m0 >= offs[E_N]) return;
  int e = 0;
  while (m0 >= offs[e + 1]) ++e;
  if (tid < TM) {
    const bool valid = (m0 + tid) < (offs[e] + cnt_al[e]);
    rowidx[tid] = valid ? order[m0 + tid] : B_N;   // pad -> zero row
  }
  __syncthreads();
  const unsigned short* Wt1e = Wt1 + (size_t)e * HP * D_K;

  const int l = tid & 63, w = tid >> 6;
  const int r4 = l >> 2;
  const int sg = (r4 ^ (r4 >> 2)) & 3;
  const int g8 = ((l & 3) ^ sg) * 8;
  const int t0 = nb * 8 + 2 * w;            // first of two 16-col tiles (0..24)
  const bool act0 = (t0 < 25);
  const bool act1 = (t0 + 1 < 25);
  const unsigned short* gA = xc + (size_t)rowidx[16 * w + r4] * D_K + g8;
  const unsigned short* gB0 = Wt1e + (size_t)(t0 * 16 + r4) * D_K + g8;
  const unsigned short* gB1 = gB0 + (size_t)16 * D_K;

  const int ln = l & 15, q = l >> 4;
  const int sr = (ln ^ (ln >> 2)) & 3;
  const int cq = (q ^ sr) * 8;

  f32x4 acc[4][2] = {};

  // prologue: stage K 0..63 (both 32-wide halves) into buf 0
#pragma unroll
  for (int ks = 0; ks < 2; ++ks) {
    GLDS(gA + ks * 32, &As[ks * 2048 + 16 * w * 32]);
    if (act0) GLDS(gB0 + ks * 32, &Bs[ks * 4096 + (2 * w + 0) * 512]);
    if (act1) GLDS(gB1 + ks * 32, &Bs[ks * 4096 + (2 * w + 1) * 512]);
  }

  for (int k0 = 0; k0 < D_K; k0 += 64) {    // 16 iterations
    const int cur = (k0 >> 6) & 1;
    const int nxt = cur ^ 1;
    __syncthreads();               // publishes buf[cur] (implicit vmcnt(0))
    if (k0 + 64 < D_K) {
#pragma unroll
      for (int ks = 0; ks < 2; ++ks) {
        const int kg = k0 + 64 + ks * 32;
        GLDS(gA + kg, &As[nxt * 4096 + ks * 2048 + 16 * w * 32]);
        if (act0) GLDS(gB0 + kg, &Bs[nxt * 8192 + ks * 4096 + (2 * w + 0) * 512]);
        if (act1) GLDS(gB1 + kg, &Bs[nxt * 8192 + ks * 4096 + (2 * w + 1) * 512]);
      }
    }
    if (act0) {
#pragma unroll
      for (int ks = 0; ks < 2; ++ks) {
        const unsigned short* Ab = &As[cur * 4096 + ks * 2048];
        const unsigned short* Bb = &Bs[cur * 8192 + ks * 4096];
        bf16x8 af[4];
#pragma unroll
        for (int i = 0; i < 4; ++i)
          af[i] = *(const bf16x8*)&Ab[(16 * i + ln) * 32 + cq];
        bf16x8 b0f = *(const bf16x8*)&Bb[(2 * w + 0) * 512 + ln * 32 + cq];
#pragma unroll
        for (int i = 0; i < 4; ++i)
          acc[i][0] = __builtin_amdgcn_mfma_f32_16x16x32_bf16(b0f, af[i], acc[i][0], 0, 0, 0);
        if (act1) {
          bf16x8 b1f = *(const bf16x8*)&Bb[(2 * w + 1) * 512 + ln * 32 + cq];
#pragma unroll
          for (int i = 0; i < 4; ++i)
            acc[i][1] = __builtin_amdgcn_mfma_f32_16x16x32_bf16(b1f, af[i], acc[i][1], 0, 0, 0);
        }
      }
    }
  }

  // swapped layout: lane holds m = m0+16i+ln (col=lane&15), n = tile*16+4q+reg.
#pragma unroll
  for (int j = 0; j < 2; ++j) {
    if (j == 0 ? act0 : act1) {
      const int n4 = (t0 + j) * 16 + 4 * q;          // always < 400
      const float4 bv = *(const float4*)&b1[e * H_N + n4];
#pragma unroll
      for (int i = 0; i < 4; ++i) {
        const size_t m = (size_t)(m0 + 16 * i + ln);
        uint2 o;
        o.x = pkbf(fmaxf(acc[i][j][0] + bv.x, 0.f), fmaxf(acc[i][j][1] + bv.y, 0.f));
        o.y = pkbf(fmaxf(acc[i][j][2] + bv.z, 0.f), fmaxf(acc[i][j][3] + bv.w, 0.f));
        *(uint2*)&h1buf[m * HP + n4] = o;
      }
    }
  }
  // h1 pad cols [400,416) stay unwritten: Wt2 rows there are zero.
}

// ---------------- GEMM2 (byte-exact best-measured R2 config) ----------------
// grid (144,4) swizzled; two 16-col tiles/wave; BK=64 double-sub-tile K-step.
// K=416 -> 7 iterations, last does only the low 32-wide half.
__global__ __launch_bounds__(256) void gemm2_kernel(const unsigned short* __restrict__ h1buf,
                                                    const unsigned short* __restrict__ Wt2,
                                                    const float* __restrict__ b2,
                                                    const int* __restrict__ off_al,
                                                    const int* __restrict__ cnt_al,
                                                    const int* __restrict__ order,
                                                    float* __restrict__ out) {
  __shared__ unsigned short As[2 * 2 * 2048];
  __shared__ unsigned short Bs[2 * 2 * 4096];
  __shared__ int offs[E_N + 1];
  __shared__ int rowidx[TM];
  const int tid = threadIdx.x;
  int mt, nb;
  swz_decode(blockIdx.x, blockIdx.y, mt, nb);
  const int m0 = mt * TM;
  if (tid <= E_N) offs[tid] = off_al[tid];
  __syncthreads();
  if (m0 >= offs[E_N]) return;
  int e = 0;
  while (m0 >= offs[e + 1]) ++e;
  if (tid < TM) {
    const bool valid = (m0 + tid) < (offs[e] + cnt_al[e]);
    rowidx[tid] = valid ? order[m0 + tid] : -1;
  }
  __syncthreads();
  const unsigned short* Wt2e = Wt2 + (size_t)e * K2_N * HP;

  const int l = tid & 63, w = tid >> 6;
  const int r4 = l >> 2;
  const int sg = (r4 ^ (r4 >> 2)) & 3;
  const int g8 = ((l & 3) ^ sg) * 8;
  const int t0 = nb * 8 + 2 * w;            // two 16-col tiles of 32 (exact)
  const unsigned short* gA = h1buf + (size_t)(m0 + 16 * w + r4) * HP + g8;
  const unsigned short* gB0 = Wt2e + (size_t)(t0 * 16 + r4) * HP + g8;
  const unsigned short* gB1 = gB0 + (size_t)16 * HP;

  const int ln = l & 15, q = l >> 4;
  const int sr = (ln ^ (ln >> 2)) & 3;
  const int cq = (q ^ sr) * 8;

  f32x4 acc[4][2] = {};

  // prologue: stage K 0..63 into buf 0
#pragma unroll
  for (int ks = 0; ks < 2; ++ks) {
    GLDS(gA + ks * 32, &As[ks * 2048 + 16 * w * 32]);
    GLDS(gB0 + ks * 32, &Bs[ks * 4096 + (2 * w + 0) * 512]);
    GLDS(gB1 + ks * 32, &Bs[ks * 4096 + (2 * w + 1) * 512]);
  }

  for (int k0 = 0; k0 < HP; k0 += 64) {     // 7 iterations (last = half)
    const int cur = (k0 >> 6) & 1;
    const int nxt = cur ^ 1;
    __syncthreads();
#pragma unroll
    for (int ks = 0; ks < 2; ++ks) {
      const int kg = k0 + 64 + ks * 32;
      if (kg < HP) {
        GLDS(gA + kg, &As[nxt * 4096 + ks * 2048 + 16 * w * 32]);
        GLDS(gB0 + kg, &Bs[nxt * 8192 + ks * 4096 + (2 * w + 0) * 512]);
        GLDS(gB1 + kg, &Bs[nxt * 8192 + ks * 4096 + (2 * w + 1) * 512]);
      }
    }
#pragma unroll
    for (int ks = 0; ks < 2; ++ks) {
      if (k0 + ks * 32 < HP) {
        const unsigned short* Ab = &As[cur * 4096 + ks * 2048];
        const unsigned short* Bb = &Bs[cur * 8192 + ks * 4096];
        bf16x8 af[4];
#pragma unroll
        for (int i = 0; i < 4; ++i)
          af[i] = *(const bf16x8*)&Ab[(16 * i + ln) * 32 + cq];
        bf16x8 b0f = *(const bf16x8*)&Bb[(2 * w + 0) * 512 + ln * 32 + cq];
#pragma unroll
        for (int i = 0; i < 4; ++i)
          acc[i][0] = __builtin_amdgcn_mfma_f32_16x16x32_bf16(b0f, af[i], acc[i][0], 0, 0, 0);
        bf16x8 b1f = *(const bf16x8*)&Bb[(2 * w + 1) * 512 + ln * 32 + cq];
#pragma unroll
        for (int i = 0; i < 4; ++i)
          acc[i][1] = __builtin_amdgcn_mfma_f32_16x16x32_bf16(b1f, af[i], acc[i][1], 0, 0, 0);
      }
    }
  }

  // swapped layout: lane holds m = m0+16i+ln, n = tile*16+4q+reg (4 consecutive).
#pragma unroll
  for (int j = 0; j < 2; ++j) {
    const int n4 = (t0 + j) * 16 + 4 * q;
    const float4 bv = *(const float4*)&b2[e * K2_N + n4];
#pragma unroll
    for (int i = 0; i < 4; ++i) {
      const int s = rowidx[16 * i + ln];
      if (s >= 0) {
        float4 v;
        v.x = acc[i][j][0] + bv.x;
        v.y = acc[i][j][1] + bv.y;
        v.z = acc[i][j][2] + bv.z;
        v.w = acc[i][j][3] + bv.w;
        if (n4 < L_N) *(float4*)&out[(size_t)s * L_N + n4] = v;
        else          *(float4*)&out[(size_t)(B_N + s) * L_N + (n4 - L_N)] = v;
      }
    }
  }
}

extern "C" void kernel_launch(void* const* d_in, const int* in_sizes, int n_in,
                              void* d_out, int out_size, void* d_ws, size_t ws_size,
                              hipStream_t stream) {
  const float* x   = (const float*)d_in[0];
  const int*   idx = (const int*)d_in[1];
  const float* W1  = (const float*)d_in[2];
  const float* b1  = (const float*)d_in[3];
  const float* W2  = (const float*)d_in[4];
  const float* b2  = (const float*)d_in[5];
  float* out = (float*)d_out;

  // ws layout (bytes), total ~44.9 MB:
  // off_al@0 (68) | cnt_al@128 (64) | order@2240 (36864)
  // xc@39104 ((8192+1)x1024x2) | h1@16,818,368 (9216x416x2)
  // Wt1@24,486,080 (16x416x1024x2) | Wt2@38,117,568 (16x512x416x2)
  char* ws = (char*)d_ws;
  int* off_al = (int*)(ws + 0);
  int* cnt_al = (int*)(ws + 128);
  int* order  = (int*)(ws + 2240);
  unsigned short* xc  = (unsigned short*)(ws + 39104);
  unsigned short* h1  = (unsigned short*)(ws + 16818368);
  unsigned short* Wt1 = (unsigned short*)(ws + 24486080);
  unsigned short* Wt2 = (unsigned short*)(ws + 38117568);

  prep_kernel<<<3232, 256, 0, stream>>>(W1, W2, x, idx, Wt1, Wt2, xc,
                                        off_al, cnt_al, order);
  gemm1_kernel<<<dim3(NTILES, 4), 256, 0, stream>>>(xc, Wt1, b1, off_al, cnt_al, order, h1);
  gemm2_kernel<<<dim3(NTILES, 4), 256, 0, stream>>>(h1, Wt2, b2, off_al, cnt_al, order, out);
}